// Round 7
// baseline (197.514 us; speedup 1.0000x reference)
//
#include <hip/hip_runtime.h>
#include <hip/hip_fp16.h>
#include <hip/hip_cooperative_groups.h>

#define DIN 1024
#define H_SZ 512
#define OUT_SZ 512
#define EPSF 1e-8f

typedef __attribute__((ext_vector_type(8))) short short8v;   // 8 bf16 = 4 VGPRs
typedef __attribute__((ext_vector_type(4))) float f32x4;
typedef _Float16 half2v __attribute__((ext_vector_type(2)));

// fp32 -> bf16 (RNE)
static __device__ inline unsigned short f2bf(float f) {
    unsigned u = __float_as_uint(f);
    u = u + 0x7FFFu + ((u >> 16) & 1u);
    return (unsigned short)(u >> 16);
}

// Canberra core: 7 packed ops per 2 terms (proven rounds 3/5/6, absmax 1.5e-5).
static __device__ inline void canb2(unsigned hu, unsigned wu, unsigned& a, unsigned two) {
    unsigned mn, sm, tt, y;
    asm("v_pk_min_f16 %0, %1, %2" : "=v"(mn) : "v"(hu), "v"(wu));
    asm("v_pk_add_f16 %0, %1, %2" : "=v"(sm) : "v"(hu), "v"(wu));
    y = 0x77847784u - sm;                           // magic rcp seed (v_sub_u32)
    asm("v_pk_fma_f16 %0, %1, %2, %3 neg_lo:[1,0,0] neg_hi:[1,0,0]"
        : "=v"(tt) : "v"(sm), "v"(y), "v"(two));    // tt = 2 - sm*y
    asm("v_pk_mul_f16 %0, %1, %2" : "=v"(y) : "v"(y), "v"(tt));
    asm("v_pk_fma_f16 %0, %1, %2, %0" : "+v"(a) : "v"(mn), "v"(y));
}

// LDS union: phase A (gemm) 41KB, phase B (canberra) 66.5KB -> 2 blocks/CU.
union SMem {
    struct {
        unsigned short As[2][2][32][72];   // [khalf][buf][m][k], stride 72 (proven)
        unsigned short Bs[2][2][32][72];
        float red[4][64][4];               // k-half accumulator exchange
    } a;
    struct {
        unsigned hs[32][260];              // 32 rows x 256 uints (512 fp16) + pad
        unsigned ws[32][260];
    } b;
};

// ============ FUSED: gemm+bias+relu -> hh | Wd relu-cvt -> wh | grid.sync | canberra -> out ======
__global__ __launch_bounds__(512, 4) void fused(const float* __restrict__ x,
                                                const float* __restrict__ W1,
                                                const float* __restrict__ b1,
                                                const float* __restrict__ Wd,
                                                unsigned short* __restrict__ hh,
                                                unsigned short* __restrict__ wh,
                                                float* __restrict__ out) {
    __shared__ SMem sm;
    const int t  = threadIdx.x;
    const int b0 = blockIdx.x * 32;     // b-tile (phase A rows, phase B rows)
    const int o0 = blockIdx.y * 32;     // phase A: h-col tile; phase B: o-tile

    // ---------------- phase A: h[b0:+32][o0:+32] via MFMA, 8 waves = 4 quadrants x 2 k-halves ----
    {
        const int w  = t >> 6;
        const int l  = t & 63;
        const int q  = w & 3;
        const int kh = w >> 2;             // k-half 0/1 (== t>>8, matches staging half)
        const int m0 = (q >> 1) * 16;
        const int n0 = (q & 1) * 16;
        const int lr = l & 15;
        const int lk = (l >> 4) * 8;
        const int th = t & 255;
        const int ar = th >> 3;            // 0..31
        const int ko = (th & 7) * 8;       // 0..56

        f32x4 acc = {0.f, 0.f, 0.f, 0.f};
        const float* arow = &x [(size_t)(b0 + ar) * DIN + kh * 512 + ko];
        const float* brow = &W1[(size_t)(o0 + ar) * DIN + kh * 512 + ko];
        float4 pa0 = *reinterpret_cast<const float4*>(arow);
        float4 pa1 = *reinterpret_cast<const float4*>(arow + 4);
        float4 pb0 = *reinterpret_cast<const float4*>(brow);
        float4 pb1 = *reinterpret_cast<const float4*>(brow + 4);

        for (int k0 = 0; k0 < 512; k0 += 64) {
            const int buf = (k0 >> 6) & 1;
            short8v av, bv;
            av[0] = (short)f2bf(pa0.x); av[1] = (short)f2bf(pa0.y);
            av[2] = (short)f2bf(pa0.z); av[3] = (short)f2bf(pa0.w);
            av[4] = (short)f2bf(pa1.x); av[5] = (short)f2bf(pa1.y);
            av[6] = (short)f2bf(pa1.z); av[7] = (short)f2bf(pa1.w);
            bv[0] = (short)f2bf(pb0.x); bv[1] = (short)f2bf(pb0.y);
            bv[2] = (short)f2bf(pb0.z); bv[3] = (short)f2bf(pb0.w);
            bv[4] = (short)f2bf(pb1.x); bv[5] = (short)f2bf(pb1.y);
            bv[6] = (short)f2bf(pb1.z); bv[7] = (short)f2bf(pb1.w);
            *reinterpret_cast<short8v*>(&sm.a.As[kh][buf][ar][ko]) = av;
            *reinterpret_cast<short8v*>(&sm.a.Bs[kh][buf][ar][ko]) = bv;
            __syncthreads();   // dbuf safe: buf^1's last reads were 2 syncs back (proven r5/r6)
            if (k0 + 64 < 512) {
                pa0 = *reinterpret_cast<const float4*>(arow + k0 + 64);
                pa1 = *reinterpret_cast<const float4*>(arow + k0 + 68);
                pb0 = *reinterpret_cast<const float4*>(brow + k0 + 64);
                pb1 = *reinterpret_cast<const float4*>(brow + k0 + 68);
            }
            #pragma unroll
            for (int s = 0; s < 2; ++s) {
                const short8v af = *reinterpret_cast<const short8v*>(&sm.a.As[kh][buf][m0 + lr][s * 32 + lk]);
                const short8v bf = *reinterpret_cast<const short8v*>(&sm.a.Bs[kh][buf][n0 + lr][s * 32 + lk]);
                acc = __builtin_amdgcn_mfma_f32_16x16x32_bf16(af, bf, acc, 0, 0, 0);
            }
        }
        __syncthreads();
        if (kh == 1) {
            #pragma unroll
            for (int r = 0; r < 4; ++r) sm.a.red[q][l][r] = acc[r];
        }
        __syncthreads();
        if (kh == 0) {
            // C/D layout (m89-verified): col = lane&15, row = (lane>>4)*4 + reg
            const int col = o0 + n0 + lr;
            const float bias = b1[col];
            #pragma unroll
            for (int r = 0; r < 4; ++r) {
                const float v = acc[r] + sm.a.red[q][l][r] + bias;
                const int m = b0 + m0 + (l >> 4) * 4 + r;
                hh[(size_t)m * H_SZ + col] = __half_as_ushort(__float2half(fmaxf(v, 0.0f)));
            }
        }
        // Wd preprocess: 262144 elems == 512 blocks * 512 thr, 1 each. +0 only (no -0 bits).
        const int gid = (blockIdx.y * 32 + blockIdx.x) * 512 + t;
        const float wv0 = Wd[gid];
        wh[gid] = __half_as_ushort(__float2half(wv0 > 0.f ? wv0 : 0.f));
    }

    __threadfence();
    cooperative_groups::this_grid().sync();

    // ---------------- phase B: canberra (verbatim round-6 proven logic) ------------------------
    {
        const unsigned* hu = reinterpret_cast<const unsigned*>(hh);
        const unsigned* wu = reinterpret_cast<const unsigned*>(wh);
        #pragma unroll
        for (int r = 0; r < 4; ++r) {
            const int s = t + r * 512;
            const int row = s >> 6;
            const int c16 = s & 63;
            *reinterpret_cast<uint4*>(&sm.b.hs[row][c16 * 4]) =
                *reinterpret_cast<const uint4*>(&hu[(size_t)(b0 + row) * 256 + c16 * 4]);
            *reinterpret_cast<uint4*>(&sm.b.ws[row][c16 * 4]) =
                *reinterpret_cast<const uint4*>(&wu[(size_t)(o0 + row) * 256 + c16 * 4]);
        }
        __syncthreads();

        const int ks = t >> 7;
        const int ts = t & 127;
        const int bi = ts >> 4;
        const int oj = ts & 15;
        const unsigned two = 0x40004000u;   // {2.0h, 2.0h}

        unsigned acc[4][2] = {};
        const int base = ks * 64;
        #pragma unroll 2
        for (int g = 0; g < 16; ++g) {
            const int col = base + g * 4;
            uint4 hv[4], wv[2];
            #pragma unroll
            for (int c = 0; c < 4; ++c)
                hv[c] = *reinterpret_cast<const uint4*>(&sm.b.hs[bi + 8 * c][col]);
            #pragma unroll
            for (int d = 0; d < 2; ++d)
                wv[d] = *reinterpret_cast<const uint4*>(&sm.b.ws[oj + 16 * d][col]);
            #pragma unroll
            for (int c = 0; c < 4; ++c) {
                #pragma unroll
                for (int d = 0; d < 2; ++d) {
                    canb2(hv[c].x, wv[d].x, acc[c][d], two);
                    canb2(hv[c].y, wv[d].y, acc[c][d], two);
                    canb2(hv[c].z, wv[d].z, acc[c][d], two);
                    canb2(hv[c].w, wv[d].w, acc[c][d], two);
                }
            }
        }

        float p[8];
        #pragma unroll
        for (int c = 0; c < 4; ++c)
            #pragma unroll
            for (int d = 0; d < 2; ++d) {
                const half2v av = __builtin_bit_cast(half2v, acc[c][d]);
                p[c * 2 + d] = (float)av.x + (float)av.y;
            }

        __syncthreads();
        float* red = reinterpret_cast<float*>(&sm.b.hs[0][0]);
        if (ks > 0) {
            float* rp = &red[((size_t)(ks - 1) * 128 + ts) * 8];
            #pragma unroll
            for (int i = 0; i < 8; ++i) rp[i] = p[i];
        }
        __syncthreads();
        if (ks == 0) {
            #pragma unroll
            for (int q2 = 0; q2 < 3; ++q2) {
                const float* rp = &red[((size_t)q2 * 128 + ts) * 8];
                #pragma unroll
                for (int i = 0; i < 8; ++i) p[i] += rp[i];
            }
            #pragma unroll
            for (int c = 0; c < 4; ++c) {
                #pragma unroll
                for (int d = 0; d < 2; ++d) {
                    float dd = 512.0f - 2.0f * p[c * 2 + d] + EPSF;
                    dd = fminf(fmaxf(dd, EPSF), 1000000.0f);
                    out[(size_t)(b0 + bi + 8 * c) * OUT_SZ + o0 + oj + 16 * d] = 1.0f / dd;
                }
            }
        }
    }
}

// ============ fallback path (round-6 proven, ~44 us) if cooperative launch is rejected ==========
__global__ __launch_bounds__(256, 4) void gemm_mfma(const float* __restrict__ x,
                                                    const float* __restrict__ W1,
                                                    const float* __restrict__ b1,
                                                    const float* __restrict__ Wd,
                                                    unsigned short* __restrict__ hh,
                                                    unsigned short* __restrict__ wh) {
    __shared__ unsigned short As[2][2][32][40];
    __shared__ unsigned short Bs[2][2][32][40];
    const int t = threadIdx.x;
    const int b0 = blockIdx.x * 32;
    const int j0 = blockIdx.y * 32;
    {
        const int flat = blockIdx.y * 32 + blockIdx.x;
        const int i = flat * 512 + t * 2;
        const float2 v = *reinterpret_cast<const float2*>(&Wd[i]);
        const float a0 = v.x > 0.f ? v.x : 0.f;
        const float a1 = v.y > 0.f ? v.y : 0.f;
        const unsigned u = (unsigned)__half_as_ushort(__float2half(a0)) |
                           ((unsigned)__half_as_ushort(__float2half(a1)) << 16);
        reinterpret_cast<unsigned*>(wh)[i >> 1] = u;
    }
    const int w  = t >> 6;
    const int l  = t & 63;
    const int m0 = (w >> 1) * 16;
    const int n0 = (w & 1) * 16;
    const int lr = l & 15;
    const int lk = (l >> 4) * 8;
    const int ar = t >> 3;
    const int ak = (t & 7) * 8;
    const int kh = ak >> 5;
    const int ko = ak & 31;
    f32x4 acc = {0.f, 0.f, 0.f, 0.f};
    const float* xrow = &x[(size_t)(b0 + ar) * DIN + ak];
    const float* wrow = &W1[(size_t)(j0 + ar) * DIN + ak];
    float4 pa0 = *reinterpret_cast<const float4*>(xrow);
    float4 pa1 = *reinterpret_cast<const float4*>(xrow + 4);
    float4 pb0 = *reinterpret_cast<const float4*>(wrow);
    float4 pb1 = *reinterpret_cast<const float4*>(wrow + 4);
    for (int k0 = 0; k0 < DIN; k0 += 64) {
        const int buf = (k0 >> 6) & 1;
        short8v av, bv;
        av[0] = (short)f2bf(pa0.x); av[1] = (short)f2bf(pa0.y);
        av[2] = (short)f2bf(pa0.z); av[3] = (short)f2bf(pa0.w);
        av[4] = (short)f2bf(pa1.x); av[5] = (short)f2bf(pa1.y);
        av[6] = (short)f2bf(pa1.z); av[7] = (short)f2bf(pa1.w);
        bv[0] = (short)f2bf(pb0.x); bv[1] = (short)f2bf(pb0.y);
        bv[2] = (short)f2bf(pb0.z); bv[3] = (short)f2bf(pb0.w);
        bv[4] = (short)f2bf(pb1.x); bv[5] = (short)f2bf(pb1.y);
        bv[6] = (short)f2bf(pb1.z); bv[7] = (short)f2bf(pb1.w);
        *reinterpret_cast<short8v*>(&As[buf][kh][ar][ko]) = av;
        *reinterpret_cast<short8v*>(&Bs[buf][kh][ar][ko]) = bv;
        __syncthreads();
        if (k0 + 64 < DIN) {
            pa0 = *reinterpret_cast<const float4*>(xrow + k0 + 64);
            pa1 = *reinterpret_cast<const float4*>(xrow + k0 + 68);
            pb0 = *reinterpret_cast<const float4*>(wrow + k0 + 64);
            pb1 = *reinterpret_cast<const float4*>(wrow + k0 + 68);
        }
        #pragma unroll
        for (int s = 0; s < 2; ++s) {
            const short8v af = *reinterpret_cast<const short8v*>(&As[buf][s][m0 + lr][lk]);
            const short8v bf = *reinterpret_cast<const short8v*>(&Bs[buf][s][n0 + lr][lk]);
            acc = __builtin_amdgcn_mfma_f32_16x16x32_bf16(af, bf, acc, 0, 0, 0);
        }
    }
    const int col = j0 + n0 + lr;
    const float bias = b1[col];
    #pragma unroll
    for (int r = 0; r < 4; ++r) {
        const int m = b0 + m0 + (l >> 4) * 4 + r;
        hh[(size_t)m * H_SZ + col] =
            __half_as_ushort(__float2half(fmaxf(acc[r] + bias, 0.0f)));
    }
}

__global__ __launch_bounds__(512, 4) void canberra4(const unsigned short* __restrict__ hh,
                                                    const unsigned short* __restrict__ wh,
                                                    float* __restrict__ out) {
    __shared__ unsigned hs[32][260];
    __shared__ unsigned ws_[32][260];
    const int t = threadIdx.x;
    const int b0 = blockIdx.x * 32;
    const int o0 = blockIdx.y * 32;
    const unsigned* hu = reinterpret_cast<const unsigned*>(hh);
    const unsigned* wu = reinterpret_cast<const unsigned*>(wh);
    #pragma unroll
    for (int r = 0; r < 4; ++r) {
        const int s = t + r * 512;
        const int row = s >> 6;
        const int c16 = s & 63;
        *reinterpret_cast<uint4*>(&hs[row][c16 * 4]) =
            *reinterpret_cast<const uint4*>(&hu[(size_t)(b0 + row) * 256 + c16 * 4]);
        *reinterpret_cast<uint4*>(&ws_[row][c16 * 4]) =
            *reinterpret_cast<const uint4*>(&wu[(size_t)(o0 + row) * 256 + c16 * 4]);
    }
    __syncthreads();
    const int ks = t >> 7;
    const int ts = t & 127;
    const int bi = ts >> 4;
    const int oj = ts & 15;
    const unsigned two = 0x40004000u;
    unsigned acc[4][2] = {};
    const int base = ks * 64;
    #pragma unroll 2
    for (int g = 0; g < 16; ++g) {
        const int col = base + g * 4;
        uint4 hv[4], wv[2];
        #pragma unroll
        for (int c = 0; c < 4; ++c)
            hv[c] = *reinterpret_cast<const uint4*>(&hs[bi + 8 * c][col]);
        #pragma unroll
        for (int d = 0; d < 2; ++d)
            wv[d] = *reinterpret_cast<const uint4*>(&ws_[oj + 16 * d][col]);
        #pragma unroll
        for (int c = 0; c < 4; ++c) {
            #pragma unroll
            for (int d = 0; d < 2; ++d) {
                canb2(hv[c].x, wv[d].x, acc[c][d], two);
                canb2(hv[c].y, wv[d].y, acc[c][d], two);
                canb2(hv[c].z, wv[d].z, acc[c][d], two);
                canb2(hv[c].w, wv[d].w, acc[c][d], two);
            }
        }
    }
    float p[8];
    #pragma unroll
    for (int c = 0; c < 4; ++c)
        #pragma unroll
        for (int d = 0; d < 2; ++d) {
            const half2v av = __builtin_bit_cast(half2v, acc[c][d]);
            p[c * 2 + d] = (float)av.x + (float)av.y;
        }
    __syncthreads();
    float* red = reinterpret_cast<float*>(&hs[0][0]);
    if (ks > 0) {
        float* rp = &red[((size_t)(ks - 1) * 128 + ts) * 8];
        #pragma unroll
        for (int i = 0; i < 8; ++i) rp[i] = p[i];
    }
    __syncthreads();
    if (ks == 0) {
        #pragma unroll
        for (int q = 0; q < 3; ++q) {
            const float* rp = &red[((size_t)q * 128 + ts) * 8];
            #pragma unroll
            for (int i = 0; i < 8; ++i) p[i] += rp[i];
        }
        #pragma unroll
        for (int c = 0; c < 4; ++c) {
            #pragma unroll
            for (int d = 0; d < 2; ++d) {
                float dd = 512.0f - 2.0f * p[c * 2 + d] + EPSF;
                dd = fminf(fmaxf(dd, EPSF), 1000000.0f);
                out[(size_t)(b0 + bi + 8 * c) * OUT_SZ + o0 + oj + 16 * d] = 1.0f / dd;
            }
        }
    }
}

extern "C" void kernel_launch(void* const* d_in, const int* in_sizes, int n_in,
                              void* d_out, int out_size, void* d_ws, size_t ws_size,
                              hipStream_t stream) {
    const float* x  = (const float*)d_in[0];
    const float* W1 = (const float*)d_in[1];
    const float* b1 = (const float*)d_in[2];
    const float* Wd = (const float*)d_in[3];
    float* out = (float*)d_out;
    unsigned short* hh = (unsigned short*)d_ws;                          // 1 MB fp16 h
    unsigned short* wh = (unsigned short*)((char*)d_ws + (1u << 20));    // 0.5 MB fp16 relu(Wd)

    void* args[7] = { (void*)&x, (void*)&W1, (void*)&b1, (void*)&Wd,
                      (void*)&hh, (void*)&wh, (void*)&out };
    hipError_t err = hipLaunchCooperativeKernel(reinterpret_cast<const void*>(&fused),
                                                dim3(32, 16), dim3(512, 1, 1),
                                                args, 0, stream);
    if (err != hipSuccess) {   // cooperative rejected (e.g. by capture) -> proven 2-kernel path
        gemm_mfma<<<dim3(32, 16), 256, 0, stream>>>(x, W1, b1, Wd, hh, wh);
        canberra4<<<dim3(32, 16), 512, 0, stream>>>(hh, wh, out);
    }
}

// Round 8
// 39.938 us; speedup vs baseline: 4.9455x; 4.9455x over previous
//
#include <hip/hip_runtime.h>
#include <hip/hip_fp16.h>

#define DIN 1024
#define H_SZ 512
#define OUT_SZ 512
#define EPSF 1e-8f

typedef __attribute__((ext_vector_type(8))) short short8v;   // 8 bf16 = 4 VGPRs
typedef __attribute__((ext_vector_type(4))) float f32x4;
typedef _Float16 half2v __attribute__((ext_vector_type(2)));

// fp32 -> bf16 (RNE)
static __device__ inline unsigned short f2bf(float f) {
    unsigned u = __float_as_uint(f);
    u = u + 0x7FFFu + ((u >> 16) & 1u);
    return (unsigned short)(u >> 16);
}

// Canberra core: 7 packed ops per 2 terms (proven rounds 3/5/6, absmax 1.5e-5).
static __device__ inline void canb2(unsigned hu, unsigned wu, unsigned& a, unsigned two) {
    unsigned mn, sm, tt, y;
    asm("v_pk_min_f16 %0, %1, %2" : "=v"(mn) : "v"(hu), "v"(wu));
    asm("v_pk_add_f16 %0, %1, %2" : "=v"(sm) : "v"(hu), "v"(wu));
    y = 0x77847784u - sm;                           // magic rcp seed (v_sub_u32)
    asm("v_pk_fma_f16 %0, %1, %2, %3 neg_lo:[1,0,0] neg_hi:[1,0,0]"
        : "=v"(tt) : "v"(sm), "v"(y), "v"(two));    // tt = 2 - sm*y
    asm("v_pk_mul_f16 %0, %1, %2" : "=v"(y) : "v"(y), "v"(tt));
    asm("v_pk_fma_f16 %0, %1, %2, %0" : "+v"(a) : "v"(mn), "v"(y));
}

// ---------------- GEMM (validated inside round-7 fused): 8 waves = 4 quadrants x 2 k-halves ------
// Tile 32x32, BK=64 dbuf per k-half, LDS accumulator exchange (conflict-free b128 pattern).
// 512 blocks x 512 thr = 16 waves/CU. Also does Wd relu-cvt (1 elem/thread).
__global__ __launch_bounds__(512, 4) void gemm8(const float* __restrict__ x,
                                                const float* __restrict__ W1,
                                                const float* __restrict__ b1,
                                                const float* __restrict__ Wd,
                                                unsigned short* __restrict__ hh,
                                                unsigned short* __restrict__ wh) {
    __shared__ unsigned short As[2][2][32][72];   // [khalf][buf][m][k]
    __shared__ unsigned short Bs[2][2][32][72];
    __shared__ float red[4][64][4];               // k-half exchange: quad = lane%8, conflict-free
    const int t  = threadIdx.x;
    const int b0 = blockIdx.x * 32;
    const int o0 = blockIdx.y * 32;

    const int w  = t >> 6;
    const int l  = t & 63;
    const int q  = w & 3;
    const int kh = w >> 2;             // k-half 0/1 (== t>>8, matches staging half)
    const int m0 = (q >> 1) * 16;
    const int n0 = (q & 1) * 16;
    const int lr = l & 15;
    const int lk = (l >> 4) * 8;
    const int th = t & 255;
    const int ar = th >> 3;            // 0..31
    const int ko = (th & 7) * 8;       // 0..56

    f32x4 acc = {0.f, 0.f, 0.f, 0.f};
    const float* arow = &x [(size_t)(b0 + ar) * DIN + kh * 512 + ko];
    const float* brow = &W1[(size_t)(o0 + ar) * DIN + kh * 512 + ko];
    float4 pa0 = *reinterpret_cast<const float4*>(arow);
    float4 pa1 = *reinterpret_cast<const float4*>(arow + 4);
    float4 pb0 = *reinterpret_cast<const float4*>(brow);
    float4 pb1 = *reinterpret_cast<const float4*>(brow + 4);

    for (int k0 = 0; k0 < 512; k0 += 64) {
        const int buf = (k0 >> 6) & 1;
        short8v av, bv;
        av[0] = (short)f2bf(pa0.x); av[1] = (short)f2bf(pa0.y);
        av[2] = (short)f2bf(pa0.z); av[3] = (short)f2bf(pa0.w);
        av[4] = (short)f2bf(pa1.x); av[5] = (short)f2bf(pa1.y);
        av[6] = (short)f2bf(pa1.z); av[7] = (short)f2bf(pa1.w);
        bv[0] = (short)f2bf(pb0.x); bv[1] = (short)f2bf(pb0.y);
        bv[2] = (short)f2bf(pb0.z); bv[3] = (short)f2bf(pb0.w);
        bv[4] = (short)f2bf(pb1.x); bv[5] = (short)f2bf(pb1.y);
        bv[6] = (short)f2bf(pb1.z); bv[7] = (short)f2bf(pb1.w);
        *reinterpret_cast<short8v*>(&As[kh][buf][ar][ko]) = av;
        *reinterpret_cast<short8v*>(&Bs[kh][buf][ar][ko]) = bv;
        __syncthreads();   // dbuf safe: buf^1's last reads were 2 syncs back (proven r5-r7)
        if (k0 + 64 < 512) {
            pa0 = *reinterpret_cast<const float4*>(arow + k0 + 64);
            pa1 = *reinterpret_cast<const float4*>(arow + k0 + 68);
            pb0 = *reinterpret_cast<const float4*>(brow + k0 + 64);
            pb1 = *reinterpret_cast<const float4*>(brow + k0 + 68);
        }
        #pragma unroll
        for (int s = 0; s < 2; ++s) {
            const short8v af = *reinterpret_cast<const short8v*>(&As[kh][buf][m0 + lr][s * 32 + lk]);
            const short8v bf = *reinterpret_cast<const short8v*>(&Bs[kh][buf][n0 + lr][s * 32 + lk]);
            acc = __builtin_amdgcn_mfma_f32_16x16x32_bf16(af, bf, acc, 0, 0, 0);
        }
    }
    __syncthreads();
    if (kh == 1) {
        #pragma unroll
        for (int r = 0; r < 4; ++r) red[q][l][r] = acc[r];
    }
    __syncthreads();
    if (kh == 0) {
        // C/D layout (m89-verified): col = lane&15, row = (lane>>4)*4 + reg
        const int col = o0 + n0 + lr;
        const float bias = b1[col];
        #pragma unroll
        for (int r = 0; r < 4; ++r) {
            const float v = acc[r] + red[q][l][r] + bias;
            const int m = b0 + m0 + (l >> 4) * 4 + r;
            hh[(size_t)m * H_SZ + col] = __half_as_ushort(__float2half(fmaxf(v, 0.0f)));
        }
    }
    // Wd preprocess: 262144 elems == 512 blocks * 512 thr. +0 only (no -0 bits).
    const int gid = (blockIdx.y * 32 + blockIdx.x) * 512 + t;
    const float wv0 = Wd[gid];
    wh[gid] = __half_as_ushort(__float2half(wv0 > 0.f ? wv0 : 0.f));
}

// ---------------- Canberra: dist = 512 - 2*sum(min(h,w')/(h+w')),  sim = 1/dist ----------------
// Block: 512 thr, out-tile 32b x 32o, k-split 4, 4b x 2o register tile, 2-stage reg pipeline.
// Main-loop LDS reads: broadcast / phase-set-clean (0 conflicts measured r1-r2 pattern).
// k-reduce: TRANSPOSED layout red[i][slot] -> bank = slot%32, all lanes distinct (fixes the
// 16-way conflict that the r7 fused counters exposed: 5.9M conflict cycles).
#define LDg(g_, hv_, wv_) do {                                                   \
    const int col_ = base + (g_) * 4;                                            \
    _Pragma("unroll") for (int c_ = 0; c_ < 4; ++c_)                             \
        hv_[c_] = *reinterpret_cast<const uint4*>(&hs[bi + 8 * c_][col_]);       \
    _Pragma("unroll") for (int d_ = 0; d_ < 2; ++d_)                             \
        wv_[d_] = *reinterpret_cast<const uint4*>(&ws_[oj + 16 * d_][col_]);     \
} while (0)

#define CMPg(hv_, wv_) do {                                                      \
    _Pragma("unroll") for (int c_ = 0; c_ < 4; ++c_)                             \
        _Pragma("unroll") for (int d_ = 0; d_ < 2; ++d_) {                       \
            canb2(hv_[c_].x, wv_[d_].x, acc[c_][d_], two);                       \
            canb2(hv_[c_].y, wv_[d_].y, acc[c_][d_], two);                       \
            canb2(hv_[c_].z, wv_[d_].z, acc[c_][d_], two);                       \
            canb2(hv_[c_].w, wv_[d_].w, acc[c_][d_], two);                       \
        }                                                                        \
} while (0)

__global__ __launch_bounds__(512, 4) void canberra5(const unsigned short* __restrict__ hh,
                                                    const unsigned short* __restrict__ wh,
                                                    float* __restrict__ out) {
    __shared__ unsigned hs[32][260];
    __shared__ unsigned ws_[32][260];
    const int t = threadIdx.x;
    const int b0 = blockIdx.x * 32;
    const int o0 = blockIdx.y * 32;
    const unsigned* hu = reinterpret_cast<const unsigned*>(hh);
    const unsigned* wu = reinterpret_cast<const unsigned*>(wh);

    #pragma unroll
    for (int r = 0; r < 4; ++r) {
        const int s = t + r * 512;
        const int row = s >> 6;
        const int c16 = s & 63;
        *reinterpret_cast<uint4*>(&hs[row][c16 * 4]) =
            *reinterpret_cast<const uint4*>(&hu[(size_t)(b0 + row) * 256 + c16 * 4]);
        *reinterpret_cast<uint4*>(&ws_[row][c16 * 4]) =
            *reinterpret_cast<const uint4*>(&wu[(size_t)(o0 + row) * 256 + c16 * 4]);
    }
    __syncthreads();

    const int ks = t >> 7;
    const int ts = t & 127;
    const int bi = ts >> 4;
    const int oj = ts & 15;
    const unsigned two = 0x40004000u;   // {2.0h, 2.0h}

    unsigned acc[4][2] = {};
    const int base = ks * 64;

    uint4 hA[4], wA[2], hB[4], wB[2];
    LDg(0, hA, wA);
    #pragma unroll 2
    for (int g = 0; g < 16; g += 2) {
        LDg(g + 1, hB, wB);              // prefetch odd while computing even
        CMPg(hA, wA);
        if (g + 2 < 16) LDg(g + 2, hA, wA);
        CMPg(hB, wB);
    }

    float p[8];
    #pragma unroll
    for (int c = 0; c < 4; ++c)
        #pragma unroll
        for (int d = 0; d < 2; ++d) {
            const half2v av = __builtin_bit_cast(half2v, acc[c][d]);
            p[c * 2 + d] = (float)av.x + (float)av.y;
        }

    // conflict-free k-reduce: red[i][slot], bank = slot % 32 -> 64 lanes distinct banks
    __syncthreads();
    float* red = reinterpret_cast<float*>(&hs[0][0]);   // [8][384] floats = 12 KB
    if (ks > 0) {
        const int slot = (ks - 1) * 128 + ts;
        #pragma unroll
        for (int i = 0; i < 8; ++i) red[i * 384 + slot] = p[i];
    }
    __syncthreads();
    if (ks == 0) {
        #pragma unroll
        for (int q = 0; q < 3; ++q) {
            #pragma unroll
            for (int i = 0; i < 8; ++i) p[i] += red[i * 384 + q * 128 + ts];
        }
        #pragma unroll
        for (int c = 0; c < 4; ++c) {
            #pragma unroll
            for (int d = 0; d < 2; ++d) {
                float dd = 512.0f - 2.0f * p[c * 2 + d] + EPSF;
                dd = fminf(fmaxf(dd, EPSF), 1000000.0f);
                out[(size_t)(b0 + bi + 8 * c) * OUT_SZ + o0 + oj + 16 * d] = 1.0f / dd;
            }
        }
    }
}

extern "C" void kernel_launch(void* const* d_in, const int* in_sizes, int n_in,
                              void* d_out, int out_size, void* d_ws, size_t ws_size,
                              hipStream_t stream) {
    const float* x  = (const float*)d_in[0];
    const float* W1 = (const float*)d_in[1];
    const float* b1 = (const float*)d_in[2];
    const float* Wd = (const float*)d_in[3];
    float* out = (float*)d_out;
    unsigned short* hh = (unsigned short*)d_ws;                          // 1 MB fp16 h
    unsigned short* wh = (unsigned short*)((char*)d_ws + (1u << 20));    // 0.5 MB fp16 relu(Wd)

    gemm8<<<dim3(32, 16), 512, 0, stream>>>(x, W1, b1, Wd, hh, wh);
    canberra5<<<dim3(32, 16), 512, 0, stream>>>(hh, wh, out);
}